// Round 1
// baseline (203.227 us; speedup 1.0000x reference)
//
#include <hip/hip_runtime.h>
#include <math.h>

#define MM 4
#define BB 128
#define CC 10
#define KK 32
#define FF 512
#define NZ 512
#define HH 512
#define NP (CC * KK)        // 320 prototype rows per model
#define KIN1 (NZ + CC)      // 522
#define OUTW (FF * CC)      // 5120

#define BM 64
#define BN 64
#define BKT 16

// ---------------- K1: h = relu(be_fc(proto_in, W1, r1, s1, b1)) ----------------
// proto_in = [noise | onehot]; onehot contributes a single term per row.
__global__ __launch_bounds__(256) void k_proto_fc1(
    const float* __restrict__ noise, const float* __restrict__ W1,
    const float* __restrict__ r1, const float* __restrict__ s1,
    const float* __restrict__ b1, float* __restrict__ h)
{
    const int m  = blockIdx.z;
    const int n0 = blockIdx.y * BM;
    const int o0 = blockIdx.x * BN;
    __shared__ float As[BM][BKT + 1];
    __shared__ float Bs[BKT][BN + 1];
    const int t = threadIdx.x;
    const int tx = t % 16, ty = t / 16;
    float acc[4][4] = {};

    for (int k0 = 0; k0 < NZ; k0 += BKT) {
#pragma unroll
        for (int q = 0; q < 4; ++q) {
            int e = t + q * 256;
            int row = e / BKT, kk = e % BKT;
            As[row][kk] = noise[(size_t)(n0 + row) * NZ + (k0 + kk)] * r1[m * KIN1 + k0 + kk];
        }
#pragma unroll
        for (int q = 0; q < 4; ++q) {
            int e = t + q * 256;
            int kk = e / BN, col = e % BN;
            Bs[kk][col] = W1[(size_t)(k0 + kk) * HH + (o0 + col)];
        }
        __syncthreads();
#pragma unroll
        for (int kk = 0; kk < BKT; ++kk) {
            float a[4], b[4];
#pragma unroll
            for (int i = 0; i < 4; ++i) a[i] = As[ty + 16 * i][kk];
#pragma unroll
            for (int j = 0; j < 4; ++j) b[j] = Bs[kk][tx + 16 * j];
#pragma unroll
            for (int i = 0; i < 4; ++i)
#pragma unroll
                for (int j = 0; j < 4; ++j)
                    acc[i][j] += a[i] * b[j];
        }
        __syncthreads();
    }

#pragma unroll
    for (int i = 0; i < 4; ++i) {
        int n = n0 + ty + 16 * i;          // row within model's 320
        int cn = n / KK;                   // class of this prototype row
        float rh = r1[m * KIN1 + NZ + cn];
#pragma unroll
        for (int j = 0; j < 4; ++j) {
            int o = o0 + tx + 16 * j;
            float v = acc[i][j] + rh * W1[(size_t)(NZ + cn) * HH + o];
            v = v * s1[m * HH + o] + b1[m * HH + o];
            h[((size_t)m * NP + n) * HH + o] = fmaxf(v, 0.0f);
        }
    }
}

// ---------------- K2: proto = be_fc(h, W2, r2, s2, b2) ----------------
__global__ __launch_bounds__(256) void k_proto_fc2(
    const float* __restrict__ h, const float* __restrict__ W2,
    const float* __restrict__ r2, const float* __restrict__ s2,
    const float* __restrict__ b2, float* __restrict__ proto)
{
    const int m  = blockIdx.z;
    const int n0 = blockIdx.y * BM;
    const int o0 = blockIdx.x * BN;
    __shared__ float As[BM][BKT + 1];
    __shared__ float Bs[BKT][BN + 1];
    const int t = threadIdx.x;
    const int tx = t % 16, ty = t / 16;
    float acc[4][4] = {};

    for (int k0 = 0; k0 < HH; k0 += BKT) {
#pragma unroll
        for (int q = 0; q < 4; ++q) {
            int e = t + q * 256;
            int row = e / BKT, kk = e % BKT;
            As[row][kk] = h[((size_t)m * NP + n0 + row) * HH + (k0 + kk)] * r2[m * HH + k0 + kk];
        }
#pragma unroll
        for (int q = 0; q < 4; ++q) {
            int e = t + q * 256;
            int kk = e / BN, col = e % BN;
            Bs[kk][col] = W2[(size_t)(k0 + kk) * FF + (o0 + col)];
        }
        __syncthreads();
#pragma unroll
        for (int kk = 0; kk < BKT; ++kk) {
            float a[4], b[4];
#pragma unroll
            for (int i = 0; i < 4; ++i) a[i] = As[ty + 16 * i][kk];
#pragma unroll
            for (int j = 0; j < 4; ++j) b[j] = Bs[kk][tx + 16 * j];
#pragma unroll
            for (int i = 0; i < 4; ++i)
#pragma unroll
                for (int j = 0; j < 4; ++j)
                    acc[i][j] += a[i] * b[j];
        }
        __syncthreads();
    }

#pragma unroll
    for (int i = 0; i < 4; ++i) {
        int n = n0 + ty + 16 * i;
#pragma unroll
        for (int j = 0; j < 4; ++j) {
            int o = o0 + tx + 16 * j;
            float v = acc[i][j] * s2[m * FF + o] + b2[m * FF + o];
            proto[((size_t)m * NP + n) * FF + o] = v;
        }
    }
}

// ---------------- K2b: pnormsum[m,c] = sum_k ||p_k||^2 ----------------
__global__ __launch_bounds__(256) void k_pnorm(
    const float* __restrict__ proto, float* __restrict__ pnormsum)
{
    const int mc = blockIdx.x;           // m*CC + c
    const int m = mc / CC, c = mc % CC;
    const size_t base = ((size_t)m * NP + (size_t)c * KK) * FF;
    const int t = threadIdx.x;
    float s = 0.0f;
    for (int e = t; e < KK * FF; e += 256) {
        float v = proto[base + e];
        s += v * v;
    }
#pragma unroll
    for (int off = 32; off > 0; off >>= 1) s += __shfl_down(s, off, 64);
    __shared__ float red[4];
    if ((t & 63) == 0) red[t >> 6] = s;
    __syncthreads();
    if (t == 0) pnormsum[mc] = red[0] + red[1] + red[2] + red[3];
}

// ---------------- K3: z = be_fc(x, W_lw, r_lw, s_lw) ----------------
__global__ __launch_bounds__(256) void k_lastlayer(
    const float* __restrict__ x, const float* __restrict__ Wlw,
    const float* __restrict__ rlw, const float* __restrict__ slw,
    float* __restrict__ z)
{
    const int m  = blockIdx.z;
    const int n0 = blockIdx.y * BM;      // batch tile (0 or 64)
    const int o0 = blockIdx.x * BN;      // output col tile (0..5056)
    __shared__ float As[BM][BKT + 1];
    __shared__ float Bs[BKT][BN + 1];
    const int t = threadIdx.x;
    const int tx = t % 16, ty = t / 16;
    float acc[4][4] = {};

    for (int k0 = 0; k0 < FF; k0 += BKT) {
#pragma unroll
        for (int q = 0; q < 4; ++q) {
            int e = t + q * 256;
            int row = e / BKT, kk = e % BKT;
            As[row][kk] = x[((size_t)m * BB + n0 + row) * FF + (k0 + kk)] * rlw[m * FF + k0 + kk];
        }
#pragma unroll
        for (int q = 0; q < 4; ++q) {
            int e = t + q * 256;
            int kk = e / BN, col = e % BN;
            Bs[kk][col] = Wlw[(size_t)(k0 + kk) * OUTW + (o0 + col)];
        }
        __syncthreads();
#pragma unroll
        for (int kk = 0; kk < BKT; ++kk) {
            float a[4], b[4];
#pragma unroll
            for (int i = 0; i < 4; ++i) a[i] = As[ty + 16 * i][kk];
#pragma unroll
            for (int j = 0; j < 4; ++j) b[j] = Bs[kk][tx + 16 * j];
#pragma unroll
            for (int i = 0; i < 4; ++i)
#pragma unroll
                for (int j = 0; j < 4; ++j)
                    acc[i][j] += a[i] * b[j];
        }
        __syncthreads();
    }

#pragma unroll
    for (int i = 0; i < 4; ++i) {
        int b = n0 + ty + 16 * i;
#pragma unroll
        for (int j = 0; j < 4; ++j) {
            int o = o0 + tx + 16 * j;
            float v = acc[i][j] * slw[(size_t)m * OUTW + o];
            z[((size_t)m * BB + b) * OUTW + o] = v;
        }
    }
}

// ---------------- K4: distances + exp ----------------
// logit[m,b,c] = -(K*||z||^2 - 2*sum_k z.p_k + sum_k ||p_k||^2) / (2*K*F)
__global__ __launch_bounds__(256) void k_dist(
    const float* __restrict__ z, const float* __restrict__ proto,
    const float* __restrict__ pnormsum, float* __restrict__ out)
{
    const int bt = blockIdx.x;           // batch tile of 32
    const int c  = blockIdx.y;
    const int m  = blockIdx.z;
    const int b0 = bt * 32;
    __shared__ float Zs[32][33];
    __shared__ float Ps[32][33];
    const int t = threadIdx.x;
    const int tx = t % 32, ty = t / 32;  // ty in [0,8)
    float dot[4] = {}, zn[4] = {};

    for (int f0 = 0; f0 < FF; f0 += 32) {
#pragma unroll
        for (int q = 0; q < 4; ++q) {
            int e = t + q * 256;
            int bl = e / 32, ff = e % 32;
            Zs[bl][ff] = z[((size_t)(m * BB + b0 + bl)) * OUTW + (size_t)(f0 + ff) * CC + c];
        }
#pragma unroll
        for (int q = 0; q < 4; ++q) {
            int e = t + q * 256;
            int kk = e / 32, ff = e % 32;
            Ps[kk][ff] = proto[((size_t)m * NP + (size_t)c * KK + kk) * FF + f0 + ff];
        }
        __syncthreads();
        // hoist this thread's P row (k = tx) into registers
        float preg[32];
#pragma unroll
        for (int ff = 0; ff < 32; ++ff) preg[ff] = Ps[tx][ff];
#pragma unroll
        for (int r = 0; r < 4; ++r) {
            int bl = ty * 4 + r;
            float zv = Zs[bl][tx];
            zn[r] += zv * zv;            // f-slice tx of ||z||^2
            float d = 0.0f;
#pragma unroll
            for (int ff = 0; ff < 32; ++ff)
                d += Zs[bl][ff] * preg[ff];
            dot[r] += d;                 // dot for k = tx
        }
        __syncthreads();
    }

    // reduce over the 32 tx lanes: sum over k for dot, sum over f-slices for zn
#pragma unroll
    for (int r = 0; r < 4; ++r) {
#pragma unroll
        for (int off = 16; off > 0; off >>= 1) {
            dot[r] += __shfl_xor(dot[r], off, 32);
            zn[r]  += __shfl_xor(zn[r], off, 32);
        }
    }
    if (tx == 0) {
        const float pn = pnormsum[m * CC + c];
        const float inv = 1.0f / (2.0f * (float)KK * (float)FF);  // SIGMA=1
#pragma unroll
        for (int r = 0; r < 4; ++r) {
            int b = b0 + ty * 4 + r;
            float logit = -((float)KK * zn[r] - 2.0f * dot[r] + pn) * inv;
            out[(size_t)(m * BB + b) * CC + c] = expf(logit);
        }
    }
}

extern "C" void kernel_launch(void* const* d_in, const int* in_sizes, int n_in,
                              void* d_out, int out_size, void* d_ws, size_t ws_size,
                              hipStream_t stream) {
    const float* x     = (const float*)d_in[0];
    const float* noise = (const float*)d_in[1];
    const float* W_lw  = (const float*)d_in[2];
    const float* r_lw  = (const float*)d_in[3];
    const float* s_lw  = (const float*)d_in[4];
    const float* W1    = (const float*)d_in[5];
    const float* r1    = (const float*)d_in[6];
    const float* s1    = (const float*)d_in[7];
    const float* b1    = (const float*)d_in[8];
    const float* W2    = (const float*)d_in[9];
    const float* r2    = (const float*)d_in[10];
    const float* s2    = (const float*)d_in[11];
    const float* b2    = (const float*)d_in[12];
    float* out = (float*)d_out;

    float* ws = (float*)d_ws;
    float* h     = ws;                            // 4*320*512 = 655360
    float* proto = h + (size_t)MM * NP * HH;      // 655360
    float* pnorm = proto + (size_t)MM * NP * FF;  // 40
    float* z     = pnorm + 64;                    // 4*128*5120 = 2621440

    k_proto_fc1<<<dim3(HH / BN, NP / BM, MM), 256, 0, stream>>>(noise, W1, r1, s1, b1, h);
    k_proto_fc2<<<dim3(FF / BN, NP / BM, MM), 256, 0, stream>>>(h, W2, r2, s2, b2, proto);
    k_pnorm<<<MM * CC, 256, 0, stream>>>(proto, pnorm);
    k_lastlayer<<<dim3(OUTW / BN, BB / BM, MM), 256, 0, stream>>>(x, W_lw, r_lw, s_lw, z);
    k_dist<<<dim3(BB / 32, CC, MM), 256, 0, stream>>>(z, proto, pnorm, out);
}

// Round 2
// 85.510 us; speedup vs baseline: 2.3767x; 2.3767x over previous
//
#include <hip/hip_runtime.h>
#include <math.h>

#define MM 4
#define BB 128
#define CC 10
#define KK 32
#define FF 512
#define HH 512
#define NP 320            // C*K rows per model
#define K1P 544           // padded (512 noise + 10 onehot + 22 zero)
#define OUTW 5120         // F*C

using bf16x8 = __attribute__((ext_vector_type(8))) short;
using f32x4  = __attribute__((ext_vector_type(4))) float;

__device__ __forceinline__ unsigned short f2bf(float f) {
    unsigned int u = __float_as_uint(f);
    u += 0x7FFFu + ((u >> 16) & 1u);          // round-to-nearest-even
    return (unsigned short)(u >> 16);
}

// ---------- transpose + convert: W[K][N] f32 -> Wt[N][Kp] bf16 (zero-fill k>=K) ----------
__global__ __launch_bounds__(256) void k_tconv(
    const float* __restrict__ W, unsigned short* __restrict__ Wt,
    int K, int N, int Kp)
{
    __shared__ unsigned short T[64][65];
    const int t = threadIdx.x;
    const int n0 = blockIdx.x * 64;
    const int k0 = blockIdx.y * 64;
#pragma unroll
    for (int p = 0; p < 4; ++p) {
        int kk = (t >> 4) + p * 16;
        int nn = (t & 15) * 4;
        int gk = k0 + kk;
        float4 v;
        if (gk < K) v = *(const float4*)(W + (size_t)gk * N + n0 + nn);
        else { v.x = 0.f; v.y = 0.f; v.z = 0.f; v.w = 0.f; }
        T[nn + 0][kk] = f2bf(v.x);
        T[nn + 1][kk] = f2bf(v.y);
        T[nn + 2][kk] = f2bf(v.z);
        T[nn + 3][kk] = f2bf(v.w);
    }
    __syncthreads();
#pragma unroll
    for (int p = 0; p < 2; ++p) {
        int n  = (t >> 3) + p * 32;
        int kg = t & 7;
        int gk = k0 + kg * 8;
        if (gk < Kp) {
            union { unsigned short u[8]; uint4 v; } o;
#pragma unroll
            for (int q = 0; q < 8; ++q) o.u[q] = T[n][kg * 8 + q];
            *(uint4*)(Wt + (size_t)(n0 + n) * Kp + gk) = o.v;
        }
    }
}

// ---------- build A1 [1280][544] bf16: [noise*r1 | onehot*r1 | 0] ----------
__global__ __launch_bounds__(256) void k_build_a1(
    const float* __restrict__ noise, const float* __restrict__ r1,
    unsigned short* __restrict__ A1)
{
    const int id = blockIdx.x * 256 + threadIdx.x;   // 1280*68 = 87040 exact
    const int row = id / 68, g = id % 68;
    const int m = row / NP, n = row % NP;
    union { unsigned short u[8]; uint4 v; } o;
    if (g < 64) {
        const float* np = noise + (size_t)n * 512 + g * 8;
        const float* rp = r1 + (size_t)m * 522 + g * 8;
#pragma unroll
        for (int q = 0; q < 8; ++q) o.u[q] = f2bf(np[q] * rp[q]);
    } else {
        const int colbase = 512 + (g - 64) * 8;
        const int cn = n >> 5;
#pragma unroll
        for (int q = 0; q < 8; ++q) {
            int col = colbase + q;
            float v = (col - 512 == cn) ? r1[(size_t)m * 522 + col] : 0.f;
            o.u[q] = f2bf(v);
        }
    }
    *(uint4*)(A1 + (size_t)row * K1P + g * 8) = o.v;
}

// ---------- xr [512][512] bf16 = x * r_lw ----------
__global__ __launch_bounds__(256) void k_conv_xr(
    const float* __restrict__ x, const float* __restrict__ r_lw,
    unsigned short* __restrict__ xr)
{
    const int id = blockIdx.x * 256 + threadIdx.x;   // 512*64 = 32768
    const int row = id >> 6, g = id & 63;
    const int m = row >> 7;
    const float* xp = x + (size_t)row * 512 + g * 8;
    const float* rp = r_lw + (size_t)m * 512 + g * 8;
    union { unsigned short u[8]; uint4 v; } o;
#pragma unroll
    for (int q = 0; q < 8; ++q) o.u[q] = f2bf(xp[q] * rp[q]);
    *(uint4*)(xr + (size_t)row * 512 + g * 8) = o.v;
}

// ---------- MFMA GEMM: C[M][N] = A[M][Kd] * Bt[N][Kd]^T, 128x128 tile, 4 waves ----------
// EPI 0: v = relu(acc*s+b) * rpost -> bf16   (fc1 -> A2)
// EPI 1: v = acc*s + b             -> f32    (fc2 -> proto)
// EPI 2: v = acc*s                 -> f32    (z)
template<int EPI, int KD, int RPM, int NCOLS>
__global__ __launch_bounds__(256) void k_gemm(
    const unsigned short* __restrict__ A, const unsigned short* __restrict__ Bt,
    const float* __restrict__ s, const float* __restrict__ bias,
    const float* __restrict__ rpost, void* __restrict__ outv)
{
    __shared__ unsigned short As[128][32];
    __shared__ unsigned short Bs[128][32];
    const int t = threadIdx.x;
    const int lane = t & 63;
    const int w = t >> 6;
    const int wr = w >> 1, wc = w & 1;
    const int l15 = lane & 15, l4 = lane >> 4;
    const int rowT = blockIdx.y * 128;
    const int colT = blockIdx.x * 128;

    // staging: thread t covers row srow, k-half skh (16 bf16 = 2 x uint4)
    const int srow = t >> 1;
    const int skh  = t & 1;
    const int sw   = (srow >> 1) & 3;
    const int g0   = (skh * 2) ^ sw;
    const int g1   = (skh * 2 + 1) ^ sw;
    const uint4* gA = (const uint4*)(A + (size_t)(rowT + srow) * KD);
    const uint4* gB = (const uint4*)(Bt + (size_t)(colT + srow) * KD);

    int offA[4], offB[4];
#pragma unroll
    for (int i = 0; i < 4; ++i) {
        int rA = wr * 64 + i * 16 + l15;
        offA[i] = rA * 32 + ((l4 ^ ((rA >> 1) & 3)) * 8);
        int rB = wc * 64 + i * 16 + l15;
        offB[i] = rB * 32 + ((l4 ^ ((rB >> 1) & 3)) * 8);
    }

    f32x4 acc[4][4];
#pragma unroll
    for (int i = 0; i < 4; ++i)
#pragma unroll
        for (int j = 0; j < 4; ++j) acc[i][j] = (f32x4){0.f, 0.f, 0.f, 0.f};

    const unsigned short* AsF = &As[0][0];
    const unsigned short* BsF = &Bs[0][0];

#pragma unroll 1
    for (int k0 = 0; k0 < KD; k0 += 32) {
        const int kb = (k0 >> 3) + skh * 2;
        uint4 a0 = gA[kb], a1 = gA[kb + 1];
        uint4 b0 = gB[kb], b1 = gB[kb + 1];
        __syncthreads();
        *(uint4*)&As[srow][g0 * 8] = a0;
        *(uint4*)&As[srow][g1 * 8] = a1;
        *(uint4*)&Bs[srow][g0 * 8] = b0;
        *(uint4*)&Bs[srow][g1 * 8] = b1;
        __syncthreads();
        bf16x8 af[4], bfv[4];
#pragma unroll
        for (int i = 0; i < 4; ++i) af[i] = *(const bf16x8*)(AsF + offA[i]);
#pragma unroll
        for (int j = 0; j < 4; ++j) bfv[j] = *(const bf16x8*)(BsF + offB[j]);
#pragma unroll
        for (int i = 0; i < 4; ++i)
#pragma unroll
            for (int j = 0; j < 4; ++j)
                acc[i][j] = __builtin_amdgcn_mfma_f32_16x16x32_bf16(af[i], bfv[j], acc[i][j], 0, 0, 0);
    }

#pragma unroll
    for (int i = 0; i < 4; ++i) {
#pragma unroll
        for (int ir = 0; ir < 4; ++ir) {
            const int row = rowT + wr * 64 + i * 16 + l4 * 4 + ir;
            const int m = row / RPM;
            const size_t rbase = (size_t)row * NCOLS;
#pragma unroll
            for (int j = 0; j < 4; ++j) {
                const int col = colT + wc * 64 + j * 16 + l15;
                const size_t sidx = (size_t)m * NCOLS + col;
                float v = acc[i][j][ir];
                if (EPI == 0) {
                    v = v * s[sidx] + bias[sidx];
                    v = fmaxf(v, 0.f) * rpost[sidx];
                    ((unsigned short*)outv)[rbase + col] = f2bf(v);
                } else if (EPI == 1) {
                    v = v * s[sidx] + bias[sidx];
                    ((float*)outv)[rbase + col] = v;
                } else {
                    ((float*)outv)[rbase + col] = v * s[sidx];
                }
            }
        }
    }
}

// ---------- psum[m,c,f] = sum_k proto ; pn[m,c] = sum_{k,f} proto^2 ----------
__global__ __launch_bounds__(256) void k_psum(
    const float* __restrict__ proto, float* __restrict__ psum, float* __restrict__ pn)
{
    const int mc = blockIdx.x;                      // m*10 + c
    const float* base = proto + (size_t)mc * KK * FF;
    const int t = threadIdx.x;
    float sq = 0.f;
    for (int ff = t; ff < FF; ff += 256) {
        float sv = 0.f;
#pragma unroll
        for (int k = 0; k < KK; ++k) {
            float v = base[(size_t)k * FF + ff];
            sv += v;
            sq += v * v;
        }
        psum[(size_t)mc * FF + ff] = sv;
    }
#pragma unroll
    for (int off = 32; off > 0; off >>= 1) sq += __shfl_down(sq, off, 64);
    __shared__ float red[4];
    if ((t & 63) == 0) red[t >> 6] = sq;
    __syncthreads();
    if (t == 0) pn[mc] = red[0] + red[1] + red[2] + red[3];
}

// ---------- dist + exp: out[mb, c] = exp(-(K*zn - 2*cross + pn)/(2*K*F)) ----------
__global__ __launch_bounds__(256) void k_dist(
    const float* __restrict__ z, const float* __restrict__ psum,
    const float* __restrict__ pn, float* __restrict__ out)
{
    const int mb = blockIdx.x;          // 0..511
    const int m = mb >> 7;
    const int t = threadIdx.x;
    const float* zr = z + (size_t)mb * OUTW + t * 20;
    float vv[20];
    *(float4*)&vv[0]  = *(const float4*)(zr + 0);
    *(float4*)&vv[4]  = *(const float4*)(zr + 4);
    *(float4*)&vv[8]  = *(const float4*)(zr + 8);
    *(float4*)&vv[12] = *(const float4*)(zr + 12);
    *(float4*)&vv[16] = *(const float4*)(zr + 16);
    float zn[10], cr[10];
#pragma unroll
    for (int c = 0; c < 10; ++c) { zn[c] = 0.f; cr[c] = 0.f; }
#pragma unroll
    for (int idx = 0; idx < 20; ++idx) {
        const int c = idx % 10;                     // static after unroll
        const int fofs = idx / 10;                  // 0 or 1
        float v = vv[idx];
        zn[c] += v * v;
        cr[c] += v * psum[(size_t)(m * 10 + c) * FF + t * 2 + fofs];
    }
#pragma unroll
    for (int c = 0; c < 10; ++c) {
#pragma unroll
        for (int off = 32; off > 0; off >>= 1) {
            zn[c] += __shfl_down(zn[c], off, 64);
            cr[c] += __shfl_down(cr[c], off, 64);
        }
    }
    __shared__ float red[4][20];
    const int wv = t >> 6;
    if ((t & 63) == 0) {
#pragma unroll
        for (int c = 0; c < 10; ++c) { red[wv][c] = zn[c]; red[wv][10 + c] = cr[c]; }
    }
    __syncthreads();
    if (t < 10) {
        float Z = 0.f, Cr = 0.f;
#pragma unroll
        for (int q = 0; q < 4; ++q) { Z += red[q][t]; Cr += red[q][10 + t]; }
        const float inv = 1.f / (2.f * (float)KK * (float)FF);
        float logit = -((float)KK * Z - 2.f * Cr + pn[m * 10 + t]) * inv;
        out[(size_t)mb * CC + t] = expf(logit);
    }
}

extern "C" void kernel_launch(void* const* d_in, const int* in_sizes, int n_in,
                              void* d_out, int out_size, void* d_ws, size_t ws_size,
                              hipStream_t stream) {
    const float* x     = (const float*)d_in[0];
    const float* noise = (const float*)d_in[1];
    const float* W_lw  = (const float*)d_in[2];
    const float* r_lw  = (const float*)d_in[3];
    const float* s_lw  = (const float*)d_in[4];
    const float* W1    = (const float*)d_in[5];
    const float* r1    = (const float*)d_in[6];
    const float* s1    = (const float*)d_in[7];
    const float* b1    = (const float*)d_in[8];
    const float* W2    = (const float*)d_in[9];
    const float* r2    = (const float*)d_in[10];
    const float* s2    = (const float*)d_in[11];
    const float* b2    = (const float*)d_in[12];
    float* out = (float*)d_out;

    char* base = (char*)d_ws;
    float* psum = (float*)base;                       // 81,920 B
    float* pn   = (float*)(base + 81920);             // 160 B
    char* big = base + 82944;

    // phase P (prototype path)
    unsigned short* A1  = (unsigned short*)big;                 // 1,392,640
    unsigned short* W1t = (unsigned short*)(big + 1392640);     //   557,056
    unsigned short* W2t = (unsigned short*)(big + 1949696);     //   524,288
    unsigned short* A2  = (unsigned short*)(big + 2473984);     // 1,310,720
    float*          proto = (float*)(big + 3784704);            // 2,621,440

    // phase Z (reuses phase-P space; only runs after k_psum)
    unsigned short* xr   = (unsigned short*)big;                //   524,288
    unsigned short* Wlwt = (unsigned short*)(big + 524288);     // 5,242,880
    float*          z    = (float*)(big + 5767168);             // 10,485,760

    // prototype path
    k_tconv<<<dim3(8, 9), 256, 0, stream>>>(W1, W1t, 522, 512, K1P);
    k_tconv<<<dim3(8, 8), 256, 0, stream>>>(W2, W2t, 512, 512, 512);
    k_build_a1<<<340, 256, 0, stream>>>(noise, r1, A1);
    k_gemm<0, K1P, NP, HH><<<dim3(4, 10), 256, 0, stream>>>(A1, W1t, s1, b1, r2, (void*)A2);
    k_gemm<1, 512, NP, FF><<<dim3(4, 10), 256, 0, stream>>>(A2, W2t, s2, b2, nullptr, (void*)proto);
    k_psum<<<MM * CC, 256, 0, stream>>>(proto, psum, pn);

    // z path
    k_tconv<<<dim3(80, 8), 256, 0, stream>>>(W_lw, Wlwt, 512, OUTW, 512);
    k_conv_xr<<<128, 256, 0, stream>>>(x, r_lw, xr);
    k_gemm<2, 512, BB, OUTW><<<dim3(40, 4), 256, 0, stream>>>(xr, Wlwt, s_lw, nullptr, nullptr, (void*)z);

    // fused RBF distance + exp
    k_dist<<<MM * BB, 256, 0, stream>>>(z, psum, pn, out);
}

// Round 3
// 73.125 us; speedup vs baseline: 2.7792x; 1.1694x over previous
//
#include <hip/hip_runtime.h>
#include <math.h>

#define MM 4
#define BB 128
#define CC 10
#define KK 32
#define FF 512
#define HH 512
#define NP 320            // C*K rows per model
#define K1P 544           // padded k for fc1 (512 noise + 10 onehot + 22 zero)
#define OUTW 5120         // F*C

using bf16x8 = __attribute__((ext_vector_type(8))) short;
using f32x4  = __attribute__((ext_vector_type(4))) float;

__device__ __forceinline__ unsigned short f2bf(float f) {
    unsigned int u = __float_as_uint(f);
    u += 0x7FFFu + ((u >> 16) & 1u);          // round-to-nearest-even
    return (unsigned short)(u >> 16);
}

// =================== prep mega-kernel ===================
// blocks [0,72):    W1  [522][512] -> W1t [512][544] bf16 (zero-pad k)
// blocks [72,136):  W2  [512][512] -> W2t [512][512] bf16
// blocks [136,776): W_lw[512][5120]-> Wlwt[5120][512] bf16, rows remapped (c,f)
// blocks [776,1116): A1 [1280][544] = [noise*r1 | onehot*r1 | 0]
// blocks [1116,1244): xr [512][512] = x * r_lw
// blocks [1244,1365): s_r remap + zero dist + zero pn
__global__ __launch_bounds__(256) void k_prep(
    const float* __restrict__ W1, const float* __restrict__ W2,
    const float* __restrict__ W_lw, const float* __restrict__ noise,
    const float* __restrict__ r1, const float* __restrict__ x,
    const float* __restrict__ r_lw, const float* __restrict__ s_lw,
    unsigned short* __restrict__ W1t, unsigned short* __restrict__ W2t,
    unsigned short* __restrict__ Wlwt, unsigned short* __restrict__ A1,
    unsigned short* __restrict__ xr, float* __restrict__ s_r,
    float* __restrict__ dist, float* __restrict__ pn)
{
    __shared__ unsigned short T[64][65];
    const int b = blockIdx.x;
    const int t = threadIdx.x;

    if (b < 776) {
        const float* W; unsigned short* Wt; int K, N, Kp, nt, kt; bool remap = false;
        if (b < 72)       { W = W1;   Wt = W1t;  K = 522; N = 512;  Kp = 544; nt = b % 8;          kt = b / 8; }
        else if (b < 136) { int bb = b - 72;  W = W2;   Wt = W2t;  K = 512; N = 512;  Kp = 512; nt = bb % 8;  kt = bb / 8; }
        else              { int bb = b - 136; W = W_lw; Wt = Wlwt; K = 512; N = 5120; Kp = 512; nt = bb % 80; kt = bb / 80; remap = true; }
        const int n0 = nt * 64, k0 = kt * 64;
#pragma unroll
        for (int p = 0; p < 4; ++p) {
            int kk = (t >> 4) + p * 16;
            int nn = (t & 15) * 4;
            int gk = k0 + kk;
            float4 v = {0.f, 0.f, 0.f, 0.f};
            if (gk < K) v = *(const float4*)(W + (size_t)gk * N + n0 + nn);
            T[nn + 0][kk] = f2bf(v.x);
            T[nn + 1][kk] = f2bf(v.y);
            T[nn + 2][kk] = f2bf(v.z);
            T[nn + 3][kk] = f2bf(v.w);
        }
        __syncthreads();
#pragma unroll
        for (int p = 0; p < 2; ++p) {
            int n  = (t >> 3) + p * 32;
            int kg = t & 7;
            int gk = k0 + kg * 8;
            if (gk < Kp) {
                union { unsigned short u[8]; uint4 v; } o;
#pragma unroll
                for (int q = 0; q < 8; ++q) o.u[q] = T[n][kg * 8 + q];
                int gn = n0 + n;
                int dr = remap ? ((gn % 10) * 512 + gn / 10) : gn;
                *(uint4*)(Wt + (size_t)dr * Kp + gk) = o.v;
            }
        }
    } else if (b < 1116) {
        const int id = (b - 776) * 256 + t;          // 1280*68 = 87040 exact
        const int row = id / 68, g = id % 68;
        const int m = row / NP, n = row % NP;
        union { unsigned short u[8]; uint4 v; } o;
        if (g < 64) {
            const float* npnt = noise + (size_t)n * 512 + g * 8;
            const float* rp = r1 + (size_t)m * 522 + g * 8;
#pragma unroll
            for (int q = 0; q < 8; ++q) o.u[q] = f2bf(npnt[q] * rp[q]);
        } else {
            const int colbase = 512 + (g - 64) * 8;
            const int cn = n >> 5;
#pragma unroll
            for (int q = 0; q < 8; ++q) {
                int col = colbase + q;
                float v = (col - 512 == cn) ? r1[(size_t)m * 522 + col] : 0.f;
                o.u[q] = f2bf(v);
            }
        }
        *(uint4*)(A1 + (size_t)row * K1P + g * 8) = o.v;
    } else if (b < 1244) {
        const int id = (b - 1116) * 256 + t;         // 512*64 = 32768 exact
        const int row = id >> 6, g = id & 63;
        const int m = row >> 7;
        const float* xp = x + (size_t)row * 512 + g * 8;
        const float* rp = r_lw + (size_t)m * 512 + g * 8;
        union { unsigned short u[8]; uint4 v; } o;
#pragma unroll
        for (int q = 0; q < 8; ++q) o.u[q] = f2bf(xp[q] * rp[q]);
        *(uint4*)(xr + (size_t)row * 512 + g * 8) = o.v;
    } else {
        const int id = (b - 1244) * 256 + t;         // 30760 work items
        if (id < 20480) {
            const int m = id / 5120, d = id % 5120;  // d = c*512+f
            s_r[id] = s_lw[(size_t)m * 5120 + (d % 512) * 10 + d / 512];
        } else if (id < 30720) {
            dist[id - 20480] = 0.f;
        } else if (id < 30760) {
            pn[id - 30720] = 0.f;
        }
    }
}

// =================== MFMA GEMM, templated tile + epilogue ===================
// Tile: rows = 2*I*16, cols = 2*J*16; 4 waves (2x2); K-step 32; bf16 16x16x32.
// EPI 0: outv = bf16( relu(acc*s + bias) * auxr )                (fc1 -> A2)
// EPI 1: psum/pn fused reduce (I==2): outv=psum write, auxw=pn atomic
// EPI 2: zn/cr fused reduce (I==4,J==4): bias=psum read, outv=dist atomics
template<int EPI, int I, int J, int KD, int RPM, int NCOLS>
__global__ __launch_bounds__(256) void k_gemm(
    const unsigned short* __restrict__ A, const unsigned short* __restrict__ Bt,
    const float* __restrict__ s, const float* __restrict__ bias,
    const float* __restrict__ auxr, void* __restrict__ outv,
    float* __restrict__ auxw)
{
    constexpr int TR = 2 * I * 16;
    constexpr int TC = 2 * J * 16;
    constexpr int NUA = TR / 64;
    constexpr int NUB = TC / 64;
    __shared__ unsigned short As[TR][32];
    __shared__ unsigned short Bs[TC][32];
    const int t = threadIdx.x;
    const int lane = t & 63;
    const int w = t >> 6;
    const int wr = w >> 1, wc = w & 1;
    const int l15 = lane & 15, l4 = lane >> 4;
    const int rowT = blockIdx.y * TR;
    const int colT = blockIdx.x * TC;

    const unsigned short* gAp[NUA]; int stA[NUA];
#pragma unroll
    for (int u = 0; u < NUA; ++u) {
        int e = t + u * 256;
        int srow = e >> 2, g = e & 3;
        gAp[u] = A + (size_t)(rowT + srow) * KD + g * 8;
        stA[u] = srow * 32 + ((g ^ ((srow >> 1) & 3)) * 8);
    }
    const unsigned short* gBp[NUB]; int stB[NUB];
#pragma unroll
    for (int u = 0; u < NUB; ++u) {
        int e = t + u * 256;
        int srow = e >> 2, g = e & 3;
        gBp[u] = Bt + (size_t)(colT + srow) * KD + g * 8;
        stB[u] = srow * 32 + ((g ^ ((srow >> 1) & 3)) * 8);
    }

    int offA[I], offB[J];
#pragma unroll
    for (int i = 0; i < I; ++i) {
        int rA = wr * (I * 16) + i * 16 + l15;
        offA[i] = rA * 32 + ((l4 ^ ((rA >> 1) & 3)) * 8);
    }
#pragma unroll
    for (int j = 0; j < J; ++j) {
        int rB = wc * (J * 16) + j * 16 + l15;
        offB[j] = rB * 32 + ((l4 ^ ((rB >> 1) & 3)) * 8);
    }

    f32x4 acc[I][J];
#pragma unroll
    for (int i = 0; i < I; ++i)
#pragma unroll
        for (int j = 0; j < J; ++j) acc[i][j] = (f32x4){0.f, 0.f, 0.f, 0.f};

    const unsigned short* AsF = &As[0][0];
    const unsigned short* BsF = &Bs[0][0];

#pragma unroll 1
    for (int k0 = 0; k0 < KD; k0 += 32) {
        uint4 va[NUA], vb[NUB];
#pragma unroll
        for (int u = 0; u < NUA; ++u) va[u] = *(const uint4*)(gAp[u] + k0);
#pragma unroll
        for (int u = 0; u < NUB; ++u) vb[u] = *(const uint4*)(gBp[u] + k0);
        __syncthreads();
#pragma unroll
        for (int u = 0; u < NUA; ++u) *(uint4*)(const_cast<unsigned short*>(AsF) + stA[u]) = va[u];
#pragma unroll
        for (int u = 0; u < NUB; ++u) *(uint4*)(const_cast<unsigned short*>(BsF) + stB[u]) = vb[u];
        __syncthreads();
        bf16x8 af[I], bfv[J];
#pragma unroll
        for (int i = 0; i < I; ++i) af[i] = *(const bf16x8*)(AsF + offA[i]);
#pragma unroll
        for (int j = 0; j < J; ++j) bfv[j] = *(const bf16x8*)(BsF + offB[j]);
#pragma unroll
        for (int i = 0; i < I; ++i)
#pragma unroll
            for (int j = 0; j < J; ++j)
                acc[i][j] = __builtin_amdgcn_mfma_f32_16x16x32_bf16(af[i], bfv[j], acc[i][j], 0, 0, 0);
    }

    if constexpr (EPI == 0) {
        const int m = rowT / RPM;            // tile lies within one model
#pragma unroll
        for (int j = 0; j < J; ++j) {
            const int col = colT + wc * (J * 16) + j * 16 + l15;
            const float sv = s[(size_t)m * NCOLS + col];
            const float bv = bias[(size_t)m * NCOLS + col];
            const float rv = auxr[(size_t)m * NCOLS + col];
#pragma unroll
            for (int i = 0; i < I; ++i)
#pragma unroll
                for (int ir = 0; ir < 4; ++ir) {
                    const int row = rowT + wr * (I * 16) + i * 16 + l4 * 4 + ir;
                    float v = fmaxf(acc[i][j][ir] * sv + bv, 0.f) * rv;
                    ((unsigned short*)outv)[(size_t)row * NCOLS + col] = f2bf(v);
                }
        }
    } else if constexpr (EPI == 1) {
        // wave's 32 rows = one (m,c) class group
        static_assert(I == 2, "EPI1 needs 32-row waves");
        const int grow = rowT + wr * 32;
        const int m = grow / NP;
        const int c = (grow % NP) / KK;
        const int mc = m * CC + c;
        float sq = 0.f;
#pragma unroll
        for (int j = 0; j < J; ++j) {
            const int col = colT + wc * (J * 16) + j * 16 + l15;
            const float sv = s[(size_t)m * NCOLS + col];
            const float bv = bias[(size_t)m * NCOLS + col];
            float cs = 0.f;
#pragma unroll
            for (int i = 0; i < I; ++i)
#pragma unroll
                for (int ir = 0; ir < 4; ++ir) {
                    float v = acc[i][j][ir] * sv + bv;
                    cs += v;
                    sq += v * v;
                }
            cs += __shfl_xor(cs, 16, 64);
            cs += __shfl_xor(cs, 32, 64);
            if (l4 == 0) ((float*)outv)[(size_t)mc * FF + col] = cs;
        }
#pragma unroll
        for (int off = 1; off < 64; off <<= 1) sq += __shfl_xor(sq, off, 64);
        if (lane == 0) atomicAdd(&auxw[mc], sq);
    } else {
        // EPI 2: fused zn/cr; block spans one model (rows) and one class (cols)
        static_assert(I == 4 && J == 4, "EPI2 expects 128x128 tile");
        const int m = rowT / RPM;            // RPM = 128
        const int cb = colT / FF;            // class of this col tile
        float sv[J], pv[J];
#pragma unroll
        for (int j = 0; j < J; ++j) {
            const int col = colT + wc * (J * 16) + j * 16 + l15;
            sv[j] = s[(size_t)m * NCOLS + col];
            pv[j] = bias[(size_t)m * NCOLS + col];   // psum, (c,f)-ordered
        }
        float* dst = (float*)outv;
#pragma unroll
        for (int i = 0; i < I; ++i)
#pragma unroll
            for (int ir = 0; ir < 4; ++ir) {
                const int row = rowT + wr * (I * 16) + i * 16 + l4 * 4 + ir;
                float znv = 0.f, crv = 0.f;
#pragma unroll
                for (int j = 0; j < J; ++j) {
                    float v = acc[i][j][ir] * sv[j];
                    znv += v * v;
                    crv += v * pv[j];
                }
#pragma unroll
                for (int off = 1; off < 16; off <<= 1) {
                    znv += __shfl_xor(znv, off, 64);
                    crv += __shfl_xor(crv, off, 64);
                }
                if (l15 == 0) {
                    float* dp = dst + ((size_t)row * CC + cb) * 2;
                    atomicAdd(dp + 0, znv);
                    atomicAdd(dp + 1, crv);
                }
            }
    }
}

// =================== final: logits -> exp ===================
__global__ __launch_bounds__(256) void k_out(
    const float* __restrict__ dist, const float* __restrict__ pn,
    float* __restrict__ out)
{
    const int id = blockIdx.x * 256 + threadIdx.x;   // 5120 exact
    const int c = id % 10;
    const int m = (id / 10) >> 7;
    const float zn = dist[id * 2], cr = dist[id * 2 + 1];
    const float inv = 1.f / (2.f * (float)KK * (float)FF);
    out[id] = expf(-((float)KK * zn - 2.f * cr + pn[m * 10 + c]) * inv);
}

extern "C" void kernel_launch(void* const* d_in, const int* in_sizes, int n_in,
                              void* d_out, int out_size, void* d_ws, size_t ws_size,
                              hipStream_t stream) {
    const float* x     = (const float*)d_in[0];
    const float* noise = (const float*)d_in[1];
    const float* W_lw  = (const float*)d_in[2];
    const float* r_lw  = (const float*)d_in[3];
    const float* s_lw  = (const float*)d_in[4];
    const float* W1    = (const float*)d_in[5];
    const float* r1    = (const float*)d_in[6];
    const float* s1    = (const float*)d_in[7];
    const float* b1    = (const float*)d_in[8];
    const float* W2    = (const float*)d_in[9];
    const float* r2    = (const float*)d_in[10];
    const float* s2    = (const float*)d_in[11];
    const float* b2    = (const float*)d_in[12];
    float* out = (float*)d_out;

    char* base = (char*)d_ws;
    float* psum = (float*)(base + 0);                        // 81,920
    float* pn   = (float*)(base + 81920);                    // 160 (pad 256)
    float* dist = (float*)(base + 82176);                    // 40,960
    float* s_r  = (float*)(base + 123136);                   // 81,920
    unsigned short* A1   = (unsigned short*)(base + 205056); // 1,392,640
    unsigned short* W1t  = (unsigned short*)(base + 1597696);//   557,056
    unsigned short* W2t  = (unsigned short*)(base + 2154752);//   524,288
    unsigned short* A2   = (unsigned short*)(base + 2679040);// 1,310,720
    unsigned short* xr   = (unsigned short*)(base + 3989760);//   524,288
    unsigned short* Wlwt = (unsigned short*)(base + 4514048);// 5,242,880

    k_prep<<<1365, 256, 0, stream>>>(W1, W2, W_lw, noise, r1, x, r_lw, s_lw,
                                     W1t, W2t, Wlwt, A1, xr, s_r, dist, pn);
    k_gemm<0, 2, 2, K1P, NP, HH><<<dim3(8, 20), 256, 0, stream>>>(
        A1, W1t, s1, b1, r2, (void*)A2, nullptr);
    k_gemm<1, 2, 2, 512, NP, FF><<<dim3(8, 20), 256, 0, stream>>>(
        A2, W2t, s2, b2, nullptr, (void*)psum, pn);
    k_gemm<2, 4, 4, 512, BB, OUTW><<<dim3(40, 4), 256, 0, stream>>>(
        xr, Wlwt, s_r, psum, nullptr, (void*)dist, nullptr);
    k_out<<<20, 256, 0, stream>>>(dist, pn, out);
}